// Round 8
// baseline (154.221 us; speedup 1.0000x reference)
//
#include <hip/hip_runtime.h>

// NaiveFourierKANLayer: y = cos-features @ W0^T + sin-features @ W1^T + bias
// N=32768, INPUTDIM=64, OUTDIM=256, GRIDSIZE=32 -> GEMM M=32768, N=256, K=4096
//
// R10 changes vs R9 (80.1 us gemm, MfmaUtil 36.5, VALUBusy 25, conflicts 2.1M):
//  - ZERO barriers in the k-loop. A-fragments are computed PER-LANE in
//    registers (each lane needs only (wk? sin:cos)((8*quad+1+e)*x_row) for its
//    4 rows -- same chain recurrence, same (__bf16) rounding => bit-identical
//    to the old LDS image). X is staged transposed in LDS once (Xt[64][128],
//    broadcast-friendly b32 reads), then waves free-run: no ds_write, no
//    b128 A-reads, no lockstep. R9 showed the barrier-lockstep structure
//    (not the LDS port) was the bottleneck: MfmaUtil*wall ~1100 cyc vs
//    3004 cyc/kt wall with only 2 waves/SIMD to cover the serial trig chain.
//  - 2-stage software pipeline, all deps have full-iteration slack:
//    iter(kt): read x(kt+2) | compute af(kt+1) | MFMA(kt) + rolling breg
//    reload (kt+1). af/x ping-pong in named regs (static indexing).
//  - LDS 66.5KB: Xt overlaid by split-k `red` scratch (used only after the
//    single post-loop barrier). VGPR budget ~120 + 128 acc stays <=256.
//  - B path (fragment-major Wr, global->reg), split-k, epilogue: unchanged R9.

#define IDIM 64
#define ODIM 256
#define KDIM 4096
#define BM 128

typedef __attribute__((ext_vector_type(8))) unsigned short ushort8_t;
typedef __bf16 bf16x8 __attribute__((ext_vector_type(8)));
typedef float floatx4 __attribute__((ext_vector_type(4)));

__device__ __forceinline__ unsigned short f2bf_rne(float f) {
  unsigned int u = __float_as_uint(f);
  return (unsigned short)((u + 0x7FFFu + ((u >> 16) & 1u)) >> 16);
}

// ---- weight gather+convert: fc(2,256,64,32) fp32 -> Wr fragment-major bf16 ----
// Wr granule index t (16B each, 131072 total):
//   lane = t&63, j = (t>>6)&7, bb = t>>9;  bb = kt*4 + wk*2 + wn2
// holds W[o][k] for o = wn2*128 + j*16 + (lane&15),
//   c = wk, g = (lane>>4)*8 + e, i = kt
__global__ void __launch_bounds__(256) wconv(const float* __restrict__ fc,
                                             unsigned short* __restrict__ Wr) {
  int t = blockIdx.x * 256 + threadIdx.x;  // granule index 0..131071
  int lane = t & 63;
  int j = (t >> 6) & 7;
  int bb = t >> 9;
  int wn2 = bb & 1;
  int wk = (bb >> 1) & 1;
  int kt = bb >> 2;
  int o = wn2 * 128 + j * 16 + (lane & 15);
  int g0 = (lane >> 4) * 8;
  const float* src = fc + ((size_t)wk << 19) + o * 2048 + kt * 32 + g0;
  const float4 v0 = *(const float4*)(src);
  const float4 v1 = *(const float4*)(src + 4);
  ushort8_t r;
  r[0] = f2bf_rne(v0.x);
  r[1] = f2bf_rne(v0.y);
  r[2] = f2bf_rne(v0.z);
  r[3] = f2bf_rne(v0.w);
  r[4] = f2bf_rne(v1.x);
  r[5] = f2bf_rne(v1.y);
  r[6] = f2bf_rne(v1.z);
  r[7] = f2bf_rne(v1.w);
  *(ushort8_t*)(Wr + (size_t)t * 8) = r;
}

// ---- fused feature-gen + GEMM, barrier-free k-loop ----
__global__ void __launch_bounds__(512, 2) fkan_gemm(const float* __restrict__ X,
                                                    const unsigned short* __restrict__ Wr,
                                                    const float* __restrict__ bias,
                                                    float* __restrict__ out) {
  // Xt[64][128] f32 (32KB, k-loop) overlaid by red[64][260] f32 (66.5KB, epilogue)
  __shared__ __align__(16) unsigned char smem[66560];
  float* const Xt = (float*)smem;
  float* const red = (float*)smem;

  const int t = threadIdx.x;
  const int wv = t >> 6;          // wave 0..7
  const int ln = t & 63;
  const int lm = ln & 15;
  const int quad = ln >> 4;
  const int wk = wv & 1;          // cos(0)/sin(1) half of K
  const int wn2 = (wv >> 1) & 1;  // col-half (128 cols)
  const int wm2 = wv >> 2;        // row-half (64 rows)
  const int m0 = blockIdx.x * BM;

  // ---- stage X transposed: Xt[kt][row] (coalesced global reads)
  {
    int row = t >> 2;            // 0..127
    int ks = (t & 3) * 16;       // 4 strips of 16 kt
    const float* src = X + (size_t)(m0 + row) * IDIM + ks;
#pragma unroll
    for (int j = 0; j < 4; ++j) {
      float4 v = *(const float4*)(src + j * 4);
      Xt[(ks + j * 4 + 0) * 128 + row] = v.x;
      Xt[(ks + j * 4 + 1) * 128 + row] = v.y;
      Xt[(ks + j * 4 + 2) * 128 + row] = v.z;
      Xt[(ks + j * 4 + 3) * 128 + row] = v.w;
    }
  }

  // B fragment-major base for this wave's (wk, wn2): per kt an 8KB block
  const unsigned short* const bwave = Wr + (size_t)(wk * 2 + wn2) * 4096 + ln * 8;
  const float g0q = (float)(8 * quad + 1);
  const int xoff = wm2 * 64 + lm;  // + mt*16

  floatx4 acc[4][8];
#pragma unroll
  for (int a = 0; a < 4; ++a)
#pragma unroll
    for (int b = 0; b < 8; ++b)
      acc[a][b] = (floatx4){0.0f, 0.0f, 0.0f, 0.0f};

  __syncthreads();  // Xt ready; last barrier until epilogue

  // ---- x-read: 4 rows for k (quad-broadcast, bank = row%32, conflict-free)
  auto xread = [&](int k, float* xv) {
    const float* p = Xt + k * 128 + xoff;
    xv[0] = p[0];
    xv[1] = p[16];
    xv[2] = p[32];
    xv[3] = p[48];
  };

  // ---- per-lane A-fragment compute: chain-of-8, keep cos (wk=0) or sin (wk=1).
  //      Bit-identical math+rounding to the old features() LDS image.
  auto compA = [&](const float* xv, bf16x8* af) {
    const float inv2pi = 0.15915494309189535f;
#pragma unroll
    for (int mt = 0; mt < 4; ++mt) {
      float u = xv[mt] * inv2pi;  // x in revolutions
      float u0 = u * g0q;
      float c1 = __builtin_amdgcn_cosf(u);
      float s1 = __builtin_amdgcn_sinf(u);
      float C = __builtin_amdgcn_cosf(u0);
      float S = __builtin_amdgcn_sinf(u0);
      bf16x8 fb;
      if (wk == 0) {  // wave-uniform branch
        fb[0] = (__bf16)C;
#pragma unroll
        for (int j = 1; j < 8; ++j) {
          float Cn = __builtin_fmaf(C, c1, -(S * s1));
          float Sn = __builtin_fmaf(S, c1, (C * s1));
          C = Cn;
          S = Sn;
          fb[j] = (__bf16)C;
        }
      } else {
        fb[0] = (__bf16)S;
#pragma unroll
        for (int j = 1; j < 8; ++j) {
          float Cn = __builtin_fmaf(C, c1, -(S * s1));
          float Sn = __builtin_fmaf(S, c1, (C * s1));
          C = Cn;
          S = Sn;
          fb[j] = (__bf16)S;
        }
      }
      af[mt] = fb;
    }
  };

  bf16x8 breg[8];  // current kt's B fragments (rolling reload)

  // ---- MFMA cluster: 32 MFMAs; reload breg[nt] right after its last use
  auto mcluster = [&](bf16x8* af, int reload_kt, bool do_reload) {
    const unsigned short* bn = bwave + (size_t)reload_kt * 16384;
    __builtin_amdgcn_s_setprio(1);
#pragma unroll
    for (int nt = 0; nt < 8; ++nt) {
#pragma unroll
      for (int mt = 0; mt < 4; ++mt)
        acc[mt][nt] = __builtin_amdgcn_mfma_f32_16x16x32_bf16(
            af[mt], breg[nt], acc[mt][nt], 0, 0, 0);
      if (do_reload)
        breg[nt] = __builtin_bit_cast(bf16x8, *(const ushort8_t*)(bn + nt * 512));
    }
    __builtin_amdgcn_s_setprio(0);
  };

  // ---- prologue: breg <- B(0); afA = af(0); xA = x(1)
  float xA[4], xB[4], x0[4];
  bf16x8 afA[4], afB[4];
#pragma unroll
  for (int nt = 0; nt < 8; ++nt)
    breg[nt] = __builtin_bit_cast(bf16x8, *(const ushort8_t*)(bwave + nt * 512));
  xread(0, x0);
  compA(x0, afA);
  xread(1, xA);

  // ---- steady state: invariant at top of pair i: afA=af(i), xA=x(i+1), breg=B(i)
  for (int kt = 0; kt < 62; kt += 2) {
    xread(kt + 2, xB);
    compA(xA, afB);            // af(kt+1)
    mcluster(afA, kt + 1, true);   // MFMA kt, reload B(kt+1)
    xread(kt + 3, xA);
    compA(xB, afA);            // af(kt+2)
    mcluster(afB, kt + 2, true);   // MFMA kt+1, reload B(kt+2)
  }
  // tail: afA=af(62), xA=x(63), breg=B(62)
  compA(xA, afB);              // af(63)
  mcluster(afA, 63, true);     // MFMA kt=62, reload B(63)
  mcluster(afB, 0, false);     // MFMA kt=63, no reload

  // ---- split-k reduction + store: wk=1 partials via padded LDS scratch ----
  for (int half = 0; half < 2; ++half) {
    __syncthreads();
    if (wk == 1 && wm2 == half) {
#pragma unroll
      for (int mt = 0; mt < 4; ++mt)
#pragma unroll
        for (int nt = 0; nt < 8; ++nt) {
          int col = wn2 * 128 + nt * 16 + lm;
#pragma unroll
          for (int idx = 0; idx < 4; ++idx)
            red[(mt * 16 + quad * 4 + idx) * 260 + col] = acc[mt][nt][idx];
        }
    }
    __syncthreads();
    if (wk == 0 && wm2 == half) {
#pragma unroll
      for (int nt = 0; nt < 8; ++nt) {
        int col = wn2 * 128 + nt * 16 + lm;
        float bv = bias[col];
#pragma unroll
        for (int mt = 0; mt < 4; ++mt) {
          int rbase = m0 + half * 64 + mt * 16 + quad * 4;
#pragma unroll
          for (int idx = 0; idx < 4; ++idx)
            out[(size_t)(rbase + idx) * ODIM + col] =
                acc[mt][nt][idx] + red[(mt * 16 + quad * 4 + idx) * 260 + col] + bv;
        }
      }
    }
  }
}

extern "C" void kernel_launch(void* const* d_in, const int* in_sizes, int n_in,
                              void* d_out, int out_size, void* d_ws, size_t ws_size,
                              hipStream_t stream) {
  const float* x = (const float*)d_in[0];
  const float* fc = (const float*)d_in[1];
  const float* bias = (const float*)d_in[2];
  float* out = (float*)d_out;
  unsigned short* Wr = (unsigned short*)d_ws;  // 2 MB of workspace

  hipLaunchKernelGGL(wconv, dim3(512), dim3(256), 0, stream, fc, Wr);
  hipLaunchKernelGGL(fkan_gemm, dim3(256), dim3(512), 0, stream, x, Wr, bias, out);
}

// Round 9
// 132.398 us; speedup vs baseline: 1.1648x; 1.1648x over previous
//
#include <hip/hip_runtime.h>

// NaiveFourierKANLayer: y = cos-features @ W0^T + sin-features @ W1^T + bias
// N=32768, INPUTDIM=64, OUTDIM=256, GRIDSIZE=32 -> GEMM M=32768, N=256, K=4096
//
// R11 changes vs R10 (93.2 us, MfmaUtil 31, VALUBusy 57) and R9 (80.1 us,
// MfmaUtil 36.5, VALUBusy 25):
//  - R10's lesson: barrier-free needed 4x trig replication -> VALU-bound.
//    R9's lesson: 1x trig + per-kt barrier at 1 block/CU (grid 256) -> every
//    barrier is a hard CU-wide stall, nothing to cover it.
//  - R11 = R9's exact structure at HALF the block: BM=64, 256 threads,
//    4 waves (wk x wn2), grid 512 -> 2 blocks/CU. Each SIMD hosts one wave
//    from each block; when block A sits at the barrier, block B's waves run
//    MFMA (the cross-block TLP cover R4 had accidentally).
//  - Per-wave work, B register path (fragment-major Wr), feature math
//    (bit-exact), split-k, epilogue: R9-verbatim with wm2 deleted.
//  - LDS 66.5KB/block (As 16KB overlaid in red scratch) -> 2 blocks = 133KB.
//    Regs ~244/thread -> exactly 2 waves/SIMD (launch_bounds (256,2)).

#define IDIM 64
#define ODIM 256
#define KDIM 4096
#define BM 64

typedef __attribute__((ext_vector_type(8))) unsigned short ushort8_t;
typedef __bf16 bf16x8 __attribute__((ext_vector_type(8)));
typedef float floatx4 __attribute__((ext_vector_type(4)));

__device__ __forceinline__ unsigned short f2bf_rne(float f) {
  unsigned int u = __float_as_uint(f);
  return (unsigned short)((u + 0x7FFFu + ((u >> 16) & 1u)) >> 16);
}

// ---- weight gather+convert: fc(2,256,64,32) fp32 -> Wr fragment-major bf16 ----
// Wr granule index t (16B each, 131072 total):
//   lane = t&63, j = (t>>6)&7, bb = t>>9;  bb = kt*4 + wk*2 + wn2
// holds W[o][k] for o = wn2*128 + j*16 + (lane&15),
//   c = wk, g = (lane>>4)*8 + e, i = kt
__global__ void __launch_bounds__(256) wconv(const float* __restrict__ fc,
                                             unsigned short* __restrict__ Wr) {
  int t = blockIdx.x * 256 + threadIdx.x;  // granule index 0..131071
  int lane = t & 63;
  int j = (t >> 6) & 7;
  int bb = t >> 9;
  int wn2 = bb & 1;
  int wk = (bb >> 1) & 1;
  int kt = bb >> 2;
  int o = wn2 * 128 + j * 16 + (lane & 15);
  int g0 = (lane >> 4) * 8;
  const float* src = fc + ((size_t)wk << 19) + o * 2048 + kt * 32 + g0;
  const float4 v0 = *(const float4*)(src);
  const float4 v1 = *(const float4*)(src + 4);
  ushort8_t r;
  r[0] = f2bf_rne(v0.x);
  r[1] = f2bf_rne(v0.y);
  r[2] = f2bf_rne(v0.z);
  r[3] = f2bf_rne(v0.w);
  r[4] = f2bf_rne(v1.x);
  r[5] = f2bf_rne(v1.y);
  r[6] = f2bf_rne(v1.z);
  r[7] = f2bf_rne(v1.w);
  *(ushort8_t*)(Wr + (size_t)t * 8) = r;
}

// ---- fused feature-gen + GEMM ----
__global__ void __launch_bounds__(256, 2) fkan_gemm(const float* __restrict__ X,
                                                    const unsigned short* __restrict__ Wr,
                                                    const float* __restrict__ bias,
                                                    float* __restrict__ out) {
  // red[64][260] f32 = 66.5KB; As dbuf (2 x 8KB) overlaid at the front.
  // As is dead by the time red is written (barrier-separated).
  __shared__ __align__(16) unsigned char smem[66560];
  unsigned short* const AsBase = (unsigned short*)smem;  // [2][4096] ushorts
  float* const red = (float*)smem;

  const int t = threadIdx.x;
  const int wv = t >> 6;    // wave 0..3
  const int ln = t & 63;
  const int lm = ln & 15;
  const int quad = ln >> 4;
  const int wk = wv & 1;    // cos(0)/sin(1) k-half
  const int wn2 = wv >> 1;  // col-half (128 cols)
  const int m0 = blockIdx.x * BM;

  // feature role: 4 threads per row, thread q owns g = 8q+1 .. 8q+8
  const int arow = t >> 2;  // 0..63
  const int q = t & 3;
  const float g0f = (float)(8 * q + 1);

  // A write granules (kt-invariant, XOR-swizzled) — verified R2/R3 formulas
  const int ga_c = arow * 8 + (q ^ (arow & 7));
  const int ga_s = arow * 8 + ((4 + q) ^ (arow & 7));

  // B fragment-major base for this wave's (wk, wn2): per kt an 8KB block
  const unsigned short* const bwave = Wr + (size_t)(wk * 2 + wn2) * 4096 + ln * 8;

  floatx4 acc[4][8];
#pragma unroll
  for (int a = 0; a < 4; ++a)
#pragma unroll
    for (int b = 0; b < 8; ++b)
      acc[a][b] = (floatx4){0.0f, 0.0f, 0.0f, 0.0f};

  const float* xptr = X + (size_t)(m0 + arow) * IDIM;

  // ---- A staging: chain-of-8 Fourier recurrence, one (cos,sin) granule pair
  auto features = [&](float xv, int buf) {
    const float inv2pi = 0.15915494309189535f;
    float u = xv * inv2pi;  // x in revolutions
    float u0 = u * g0f;     // g0*x in revolutions
    float c1 = __builtin_amdgcn_cosf(u);
    float s1 = __builtin_amdgcn_sinf(u);
    float C = __builtin_amdgcn_cosf(u0);
    float S = __builtin_amdgcn_sinf(u0);
    bf16x8 cb, sb;
    cb[0] = (__bf16)C;
    sb[0] = (__bf16)S;
#pragma unroll
    for (int jj = 1; jj < 8; ++jj) {
      float Cn = __builtin_fmaf(C, c1, -(S * s1));
      float Sn = __builtin_fmaf(S, c1, (C * s1));
      C = Cn;
      S = Sn;
      cb[jj] = (__bf16)C;
      sb[jj] = (__bf16)S;
    }
    ushort8_t* As8 = (ushort8_t*)(AsBase + buf * 4096);
    As8[ga_c] = __builtin_bit_cast(ushort8_t, cb);
    As8[ga_s] = __builtin_bit_cast(ushort8_t, sb);
  };

  bf16x8 breg[8];  // current kt's B fragments (register-resident)

  // ---- k-step: compute kt from As[cur]+breg; rolling-prefetch breg <- ktn;
  //      features(x[ktn]) -> As[nxt]; barrier.
  auto ktstep = [&](int ktn, int cur, int nxt) {
    float xn = xptr[ktn];
    const ushort8_t* A8 = (const ushort8_t*)(AsBase + cur * 4096);
    const int ch = wk * 4 + quad;
    bf16x8 af[4];
#pragma unroll
    for (int mt = 0; mt < 4; ++mt) {
      int r = mt * 16 + lm;
      af[mt] = __builtin_bit_cast(bf16x8, A8[r * 8 + (ch ^ (r & 7))]);
    }
    const unsigned short* bn = bwave + (size_t)ktn * 16384;

    __builtin_amdgcn_s_setprio(1);
#pragma unroll
    for (int nt = 0; nt < 8; ++nt) {
#pragma unroll
      for (int mt = 0; mt < 4; ++mt)
        acc[mt][nt] = __builtin_amdgcn_mfma_f32_16x16x32_bf16(
            af[mt], breg[nt], acc[mt][nt], 0, 0, 0);
      // reload breg[nt] for kt=ktn right after its last use (WAR-safe in-order)
      breg[nt] = __builtin_bit_cast(bf16x8, *(const ushort8_t*)(bn + nt * 512));
    }
    __builtin_amdgcn_s_setprio(0);

    features(xn, nxt);  // independent VALU/trans, overlaps load returns
    __syncthreads();
  };

  // ---- tail: compute last kt, no prefetch
  auto ktlast = [&](int cur) {
    const ushort8_t* A8 = (const ushort8_t*)(AsBase + cur * 4096);
    const int ch = wk * 4 + quad;
    bf16x8 af[4];
#pragma unroll
    for (int mt = 0; mt < 4; ++mt) {
      int r = mt * 16 + lm;
      af[mt] = __builtin_bit_cast(bf16x8, A8[r * 8 + (ch ^ (r & 7))]);
    }
    __builtin_amdgcn_s_setprio(1);
#pragma unroll
    for (int nt = 0; nt < 8; ++nt)
#pragma unroll
      for (int mt = 0; mt < 4; ++mt)
        acc[mt][nt] = __builtin_amdgcn_mfma_f32_16x16x32_bf16(
            af[mt], breg[nt], acc[mt][nt], 0, 0, 0);
    __builtin_amdgcn_s_setprio(0);
  };

  // ---- prologue: breg <- kt 0; features(x0) -> buf 0
#pragma unroll
  for (int nt = 0; nt < 8; ++nt)
    breg[nt] = __builtin_bit_cast(bf16x8, *(const ushort8_t*)(bwave + nt * 512));
  features(xptr[0], 0);
  __syncthreads();

  // ---- steady state: unrolled x2 so dbuf index is compile-time
  for (int kt = 0; kt < 62; kt += 2) {
    ktstep(kt + 1, 0, 1);  // computes kt
    ktstep(kt + 2, 1, 0);  // computes kt+1
  }
  ktstep(63, 0, 1);  // computes kt=62
  ktlast(1);         // computes kt=63

  // ---- split-k reduction + store: wk=1 partials via padded LDS scratch ----
  __syncthreads();  // As reads done; red may alias As
  if (wk == 1) {
#pragma unroll
    for (int mt = 0; mt < 4; ++mt)
#pragma unroll
      for (int nt = 0; nt < 8; ++nt) {
        int col = wn2 * 128 + nt * 16 + lm;
#pragma unroll
        for (int idx = 0; idx < 4; ++idx)
          red[(mt * 16 + quad * 4 + idx) * 260 + col] = acc[mt][nt][idx];
      }
  }
  __syncthreads();
  if (wk == 0) {
#pragma unroll
    for (int nt = 0; nt < 8; ++nt) {
      int col = wn2 * 128 + nt * 16 + lm;
      float bv = bias[col];
#pragma unroll
      for (int mt = 0; mt < 4; ++mt) {
        int rbase = m0 + mt * 16 + quad * 4;
#pragma unroll
        for (int idx = 0; idx < 4; ++idx)
          out[(size_t)(rbase + idx) * ODIM + col] =
              acc[mt][nt][idx] + red[(mt * 16 + quad * 4 + idx) * 260 + col] + bv;
      }
    }
  }
}

extern "C" void kernel_launch(void* const* d_in, const int* in_sizes, int n_in,
                              void* d_out, int out_size, void* d_ws, size_t ws_size,
                              hipStream_t stream) {
  const float* x = (const float*)d_in[0];
  const float* fc = (const float*)d_in[1];
  const float* bias = (const float*)d_in[2];
  float* out = (float*)d_out;
  unsigned short* Wr = (unsigned short*)d_ws;  // 2 MB of workspace

  hipLaunchKernelGGL(wconv, dim3(512), dim3(256), 0, stream, fc, Wr);
  hipLaunchKernelGGL(fkan_gemm, dim3(512), dim3(256), 0, stream, x, Wr, bias, out);
}

// Round 10
// 128.318 us; speedup vs baseline: 1.2019x; 1.0318x over previous
//
#include <hip/hip_runtime.h>

// NaiveFourierKANLayer: y = cos-features @ W0^T + sin-features @ W1^T + bias
// N=32768, INPUTDIM=64, OUTDIM=256, GRIDSIZE=32 -> GEMM M=32768, N=256, K=4096
//
// R12 changes vs R11 (69.0 us, MfmaUtil 42, VALUBusy 28.8, conflicts 2.1M):
//  - Barrier amortized 4x: BK=256 (one __syncthreads per 4 kt). R11's budget
//    showed ~1450 cyc/kt of barrier-coupled wait vs 620 MFMA + 370 VALU +
//    150 ds; the wait is per-BARRIER, so 4 kt per barrier cuts it ~4x.
//  - As dbuf = 2 x 4 kt x 8KB = 64KB, which fits under the existing 66.5KB
//    `red` overlay -> LDS footprint/occupancy unchanged (2 blocks/CU).
//  - Super-iteration: 4x {MFMA cluster(kt) + rolling breg reload ->
//    features(kt+4) -> } barrier. Features staggered between clusters
//    (R8 pattern); every breg reload keeps ~700 cyc slack before use.
//  - Everything else R11-verbatim: per-wave work, fragment-major B register
//    path, bit-exact feature math, split-k LDS reduction, epilogue.

#define IDIM 64
#define ODIM 256
#define KDIM 4096
#define BM 64

typedef __attribute__((ext_vector_type(8))) unsigned short ushort8_t;
typedef __bf16 bf16x8 __attribute__((ext_vector_type(8)));
typedef float floatx4 __attribute__((ext_vector_type(4)));

__device__ __forceinline__ unsigned short f2bf_rne(float f) {
  unsigned int u = __float_as_uint(f);
  return (unsigned short)((u + 0x7FFFu + ((u >> 16) & 1u)) >> 16);
}

// ---- weight gather+convert: fc(2,256,64,32) fp32 -> Wr fragment-major bf16 ----
// Wr granule index t (16B each, 131072 total):
//   lane = t&63, j = (t>>6)&7, bb = t>>9;  bb = kt*4 + wk*2 + wn2
// holds W[o][k] for o = wn2*128 + j*16 + (lane&15),
//   c = wk, g = (lane>>4)*8 + e, i = kt
__global__ void __launch_bounds__(256) wconv(const float* __restrict__ fc,
                                             unsigned short* __restrict__ Wr) {
  int t = blockIdx.x * 256 + threadIdx.x;  // granule index 0..131071
  int lane = t & 63;
  int j = (t >> 6) & 7;
  int bb = t >> 9;
  int wn2 = bb & 1;
  int wk = (bb >> 1) & 1;
  int kt = bb >> 2;
  int o = wn2 * 128 + j * 16 + (lane & 15);
  int g0 = (lane >> 4) * 8;
  const float* src = fc + ((size_t)wk << 19) + o * 2048 + kt * 32 + g0;
  const float4 v0 = *(const float4*)(src);
  const float4 v1 = *(const float4*)(src + 4);
  ushort8_t r;
  r[0] = f2bf_rne(v0.x);
  r[1] = f2bf_rne(v0.y);
  r[2] = f2bf_rne(v0.z);
  r[3] = f2bf_rne(v0.w);
  r[4] = f2bf_rne(v1.x);
  r[5] = f2bf_rne(v1.y);
  r[6] = f2bf_rne(v1.z);
  r[7] = f2bf_rne(v1.w);
  *(ushort8_t*)(Wr + (size_t)t * 8) = r;
}

// ---- fused feature-gen + GEMM ----
__global__ void __launch_bounds__(256, 2) fkan_gemm(const float* __restrict__ X,
                                                    const unsigned short* __restrict__ Wr,
                                                    const float* __restrict__ bias,
                                                    float* __restrict__ out) {
  // red[64][260] f32 = 66560B; As dbuf 2 x (4 kt x 8KB) = 65536B overlaid.
  // As is dead by the time red is written (barrier-separated).
  __shared__ __align__(16) unsigned char smem[66560];
  unsigned short* const AsBase = (unsigned short*)smem;  // [2][4][4096] ushorts
  float* const red = (float*)smem;

  const int t = threadIdx.x;
  const int wv = t >> 6;    // wave 0..3
  const int ln = t & 63;
  const int lm = ln & 15;
  const int quad = ln >> 4;
  const int wk = wv & 1;    // cos(0)/sin(1) k-half
  const int wn2 = wv >> 1;  // col-half (128 cols)
  const int m0 = blockIdx.x * BM;

  // feature role: 4 threads per row, thread q owns g = 8q+1 .. 8q+8
  const int arow = t >> 2;  // 0..63
  const int q = t & 3;
  const float g0f = (float)(8 * q + 1);

  // A write granules (kt-invariant, XOR-swizzled) — verified R2/R3 formulas
  const int ga_c = arow * 8 + (q ^ (arow & 7));
  const int ga_s = arow * 8 + ((4 + q) ^ (arow & 7));

  // B fragment-major base for this wave's (wk, wn2): per kt an 8KB block
  const unsigned short* const bwave = Wr + (size_t)(wk * 2 + wn2) * 4096 + ln * 8;

  floatx4 acc[4][8];
#pragma unroll
  for (int a = 0; a < 4; ++a)
#pragma unroll
    for (int b = 0; b < 8; ++b)
      acc[a][b] = (floatx4){0.0f, 0.0f, 0.0f, 0.0f};

  const float* xptr = X + (size_t)(m0 + arow) * IDIM;

  // ---- A staging: chain-of-8 Fourier recurrence -> As[buf][j] sub-tile
  auto features = [&](float xv, int buf, int j) {
    const float inv2pi = 0.15915494309189535f;
    float u = xv * inv2pi;  // x in revolutions
    float u0 = u * g0f;     // g0*x in revolutions
    float c1 = __builtin_amdgcn_cosf(u);
    float s1 = __builtin_amdgcn_sinf(u);
    float C = __builtin_amdgcn_cosf(u0);
    float S = __builtin_amdgcn_sinf(u0);
    bf16x8 cb, sb;
    cb[0] = (__bf16)C;
    sb[0] = (__bf16)S;
#pragma unroll
    for (int jj = 1; jj < 8; ++jj) {
      float Cn = __builtin_fmaf(C, c1, -(S * s1));
      float Sn = __builtin_fmaf(S, c1, (C * s1));
      C = Cn;
      S = Sn;
      cb[jj] = (__bf16)C;
      sb[jj] = (__bf16)S;
    }
    ushort8_t* As8 = (ushort8_t*)(AsBase + buf * 16384 + j * 4096);
    As8[ga_c] = __builtin_bit_cast(ushort8_t, cb);
    As8[ga_s] = __builtin_bit_cast(ushort8_t, sb);
  };

  bf16x8 breg[8];  // current kt's B fragments (register-resident)

  // ---- MFMA cluster for one kt: af from As[buf][j]; rolling breg reload
  auto cluster = [&](int buf, int j, int reload_kt, bool do_reload) {
    const ushort8_t* A8 = (const ushort8_t*)(AsBase + buf * 16384 + j * 4096);
    const int ch = wk * 4 + quad;
    bf16x8 af[4];
#pragma unroll
    for (int mt = 0; mt < 4; ++mt) {
      int r = mt * 16 + lm;
      af[mt] = __builtin_bit_cast(bf16x8, A8[r * 8 + (ch ^ (r & 7))]);
    }
    const unsigned short* bn = bwave + (size_t)reload_kt * 16384;
    __builtin_amdgcn_s_setprio(1);
#pragma unroll
    for (int nt = 0; nt < 8; ++nt) {
#pragma unroll
      for (int mt = 0; mt < 4; ++mt)
        acc[mt][nt] = __builtin_amdgcn_mfma_f32_16x16x32_bf16(
            af[mt], breg[nt], acc[mt][nt], 0, 0, 0);
      // reload breg[nt] right after its last use (WAR-safe in-order)
      if (do_reload)
        breg[nt] = __builtin_bit_cast(bf16x8, *(const ushort8_t*)(bn + nt * 512));
    }
    __builtin_amdgcn_s_setprio(0);
  };

  // ---- super-iteration: compute kt=4s..4s+3 from As[cur], prefetch
  //      features for kt=4s+4..4s+7 into As[nxt], ONE barrier.
  auto ktquad = [&](int s, int cur, int nxt) {
    int k0 = 4 * s;
    float xn0 = xptr[k0 + 4];
    float xn1 = xptr[k0 + 5];
    float xn2 = xptr[k0 + 6];
    float xn3 = xptr[k0 + 7];
    cluster(cur, 0, k0 + 1, true);
    features(xn0, nxt, 0);
    cluster(cur, 1, k0 + 2, true);
    features(xn1, nxt, 1);
    cluster(cur, 2, k0 + 3, true);
    features(xn2, nxt, 2);
    cluster(cur, 3, k0 + 4, true);
    features(xn3, nxt, 3);
    __syncthreads();
  };

  // ---- prologue: breg <- B(0); features kt 0..3 -> buf 0
#pragma unroll
  for (int nt = 0; nt < 8; ++nt)
    breg[nt] = __builtin_bit_cast(bf16x8, *(const ushort8_t*)(bwave + nt * 512));
  features(xptr[0], 0, 0);
  features(xptr[1], 0, 1);
  features(xptr[2], 0, 2);
  features(xptr[3], 0, 3);
  __syncthreads();

  // ---- steady state: 15 super-iterations (s=0..14), unrolled x2
  for (int s = 0; s < 14; s += 2) {
    ktquad(s, 0, 1);
    ktquad(s + 1, 1, 0);
  }
  ktquad(14, 0, 1);  // computes kt 56..59, prefetches 60..63 -> buf 1

  // ---- tail: kt 60..63 from buf 1; reloads B(61..63), last no reload
  cluster(1, 0, 61, true);
  cluster(1, 1, 62, true);
  cluster(1, 2, 63, true);
  cluster(1, 3, 0, false);

  // ---- split-k reduction + store: wk=1 partials via padded LDS scratch ----
  __syncthreads();  // As reads done; red may alias As
  if (wk == 1) {
#pragma unroll
    for (int mt = 0; mt < 4; ++mt)
#pragma unroll
      for (int nt = 0; nt < 8; ++nt) {
        int col = wn2 * 128 + nt * 16 + lm;
#pragma unroll
        for (int idx = 0; idx < 4; ++idx)
          red[(mt * 16 + quad * 4 + idx) * 260 + col] = acc[mt][nt][idx];
      }
  }
  __syncthreads();
  if (wk == 0) {
#pragma unroll
    for (int nt = 0; nt < 8; ++nt) {
      int col = wn2 * 128 + nt * 16 + lm;
      float bv = bias[col];
#pragma unroll
      for (int mt = 0; mt < 4; ++mt) {
        int rbase = m0 + mt * 16 + quad * 4;
#pragma unroll
        for (int idx = 0; idx < 4; ++idx)
          out[(size_t)(rbase + idx) * ODIM + col] =
              acc[mt][nt][idx] + red[(mt * 16 + quad * 4 + idx) * 260 + col] + bv;
      }
    }
  }
}

extern "C" void kernel_launch(void* const* d_in, const int* in_sizes, int n_in,
                              void* d_out, int out_size, void* d_ws, size_t ws_size,
                              hipStream_t stream) {
  const float* x = (const float*)d_in[0];
  const float* fc = (const float*)d_in[1];
  const float* bias = (const float*)d_in[2];
  float* out = (float*)d_out;
  unsigned short* Wr = (unsigned short*)d_ws;  // 2 MB of workspace

  hipLaunchKernelGGL(wconv, dim3(512), dim3(256), 0, stream, fc, Wr);
  hipLaunchKernelGGL(fkan_gemm, dim3(512), dim3(256), 0, stream, x, Wr, bias, out);
}